// Round 4
// baseline (101.234 us; speedup 1.0000x reference)
//
#include <hip/hip_runtime.h>
#include <math.h>

#define NB      4096   // batch rows
#define T       628    // slice length
#define LW      64     // shapelet length
#define NW      565    // T - L + 1 windows
#define EW      128    // output embedding
#define XSTRIDE 8192   // C * LEN_TS
#define XOFF    2048   // DIM * LEN_TS
#define WPT     9      // windows per thread (64*9 = 576 >= 565)
#define SPPAD   640    // padded row length

// ws float layout:
//   [0..127]  combined bias: b1[e] - (shapelet . W2[e] + b2[e])
//   [128]     s_ci   [129] ss2 = sum(shapelet^2)
//   [132..]   W1T[j*128 + e] = W1[e*64 + j]
#define WS_SCI 128
#define WS_SS2 129
#define WS_W1T 132
#define WS_NEEDED ((WS_W1T + EW * LW) * sizeof(float))

__global__ __launch_bounds__(64) void prep_kernel(
        const float* __restrict__ shapelet,
        const float* __restrict__ b1,
        const float* __restrict__ W1,
        const float* __restrict__ W2,
        const float* __restrict__ b2,
        float* __restrict__ ws, int use_wt) {
    const int b = blockIdx.x;
    const int j = threadIdx.x;           // 0..63
    const float sh = shapelet[j];
    if (b < EW) {
        const int e = b;
        float dot = sh * W2[e * LW + j];
        #pragma unroll
        for (int off = 32; off; off >>= 1) dot += __shfl_xor(dot, off, 64);
        if (use_wt) ws[WS_W1T + j * EW + e] = W1[e * LW + j];
        if (j == 0) ws[e] = b1[e] - (dot + b2[e]);
    } else {
        float shn = __shfl_down(sh, 1, 64);
        float d = (j < LW - 1) ? (shn - sh) * (shn - sh) : 0.f;
        float q = sh * sh;
        #pragma unroll
        for (int off = 32; off; off >>= 1) {
            d += __shfl_xor(d, off, 64);
            q += __shfl_xor(q, off, 64);
        }
        if (j == 0) { ws[WS_SCI] = sqrtf(d + 0.001f); ws[WS_SS2] = q; }
    }
}

__global__ __launch_bounds__(64) void shapeblock_kernel(
        const float* __restrict__ x,
        const float* __restrict__ shapelet,
        const float* __restrict__ W1,
        const float* __restrict__ ws,
        float* __restrict__ out, int use_wt) {
    __shared__ __align__(16) float sp[SPPAD];

    const int b   = blockIdx.x;
    const int tid = threadIdx.x;   // one wave per block

    const float4* xr4 = (const float4*)(x + (size_t)b * XSTRIDE + XOFF);
    float4* sp4 = (float4*)sp;
    sp4[tid]      = xr4[tid];
    sp4[tid + 64] = xr4[tid + 64];
    if (tid < 29) sp4[tid + 128] = xr4[tid + 128];
    if (tid < SPPAD - T) sp[T + tid] = 0.f;
    const float s_ci = ws[WS_SCI];
    const float ss2  = ws[WS_SS2];
    __syncthreads();

    const int w0 = tid * WPT;

    float ring[WPT], acc[WPT], head[WPT];
    #pragma unroll
    for (int i = 0; i < WPT; ++i) {
        ring[i] = sp[w0 + i];
        head[i] = ring[i];
        acc[i]  = 0.f;
    }
    float sd = 0.f, sw2 = 0.f, prev = 0.f;
    #pragma unroll
    for (int j = 0; j < LW; ++j) {
        const float sj = shapelet[j];
        const float v  = ring[j % WPT];
        sw2 = fmaf(v, v, sw2);
        if (j > 0) { float d = v - prev; sd = fmaf(d, d, sd); }
        prev = v;
        #pragma unroll
        for (int i = 0; i < WPT; ++i)
            acc[i] = fmaf(ring[(j + i) % WPT], sj, acc[i]);
        if (j < LW - 1) ring[j % WPT] = sp[w0 + j + WPT];
    }

    unsigned long long key = ~0ull;
    #pragma unroll
    for (int k = 0; k < WPT; ++k) {
        const int w = w0 + k;
        float pci = sqrtf(sd + 0.001f);
        float ed  = sqrtf(fmaxf(fmaf(-2.f, acc[k], sw2 + ss2), 0.f));
        float cf  = fminf(fmaxf(pci, s_ci) / fminf(pci, s_ci), 3.0f);
        float cid = ed * cf;
        if (w < NW) {
            unsigned long long kk =
                ((unsigned long long)__float_as_uint(cid) << 32) | (unsigned)w;
            key = kk < key ? kk : key;
        }
        if (k < WPT - 1) {
            float dold = head[k + 1] - head[k];
            float dnew = ring[k + 1] - ring[k];
            sd  = fmaf(dnew, dnew, fmaf(-dold, dold, sd));
            float vold = head[k], vnew = ring[k + 1];
            sw2 = fmaf(vnew, vnew, fmaf(-vold, vold, sw2));
        }
    }

    #pragma unroll
    for (int off = 32; off; off >>= 1) {
        unsigned long long o =
            (unsigned long long)__shfl_xor((long long)key, off, 64);
        key = o < key ? o : key;
    }
    const int widx = (int)(key & 0xffffffffu);

    float a0 = ws[tid];
    float a1 = ws[tid + 64];
    if (use_wt) {
        const float* wt = ws + WS_W1T;
        #pragma unroll
        for (int j = 0; j < LW; ++j) {
            float wv = sp[widx + j];
            a0 = fmaf(wv, wt[j * EW + tid], a0);
            a1 = fmaf(wv, wt[j * EW + 64 + tid], a1);
        }
    } else {
        #pragma unroll
        for (int j = 0; j < LW; ++j) {
            float wv = sp[widx + j];
            a0 = fmaf(wv, W1[tid * LW + j], a0);
            a1 = fmaf(wv, W1[(tid + 64) * LW + j], a1);
        }
    }
    out[(size_t)b * EW + tid]      = a0;
    out[(size_t)b * EW + tid + 64] = a1;
}

extern "C" void kernel_launch(void* const* d_in, const int* in_sizes, int n_in,
                              void* d_out, int out_size, void* d_ws, size_t ws_size,
                              hipStream_t stream) {
    const float* x        = (const float*)d_in[0];
    const float* shapelet = (const float*)d_in[1];
    const float* W1       = (const float*)d_in[2];
    const float* b1       = (const float*)d_in[3];
    const float* W2       = (const float*)d_in[4];
    const float* b2       = (const float*)d_in[5];
    float* out = (float*)d_out;
    float* ws  = (float*)d_ws;

    const int use_wt = (ws_size >= WS_NEEDED) ? 1 : 0;

    prep_kernel<<<EW + 1, 64, 0, stream>>>(shapelet, b1, W1, W2, b2, ws, use_wt);
    // DISCRIMINATION EXPERIMENT: launch main kernel 4x (identical redundant
    // writes, deterministic). R3 gave F + P + M = 42.7us; this run gives
    // F + P + 4M, so M = (dur_new - 42.7)/3. Tells us whether the ~40us is
    // kernel time (optimize kernel) or fixed launch/harness cost (floor).
    for (int rep = 0; rep < 4; ++rep)
        shapeblock_kernel<<<NB, 64, 0, stream>>>(x, shapelet, W1, ws, out, use_wt);
}

// Round 5
// 25.934 us; speedup vs baseline: 3.9035x; 3.9035x over previous
//
#include <hip/hip_runtime.h>
#include <math.h>

#define NB      4096   // batch rows
#define T       628    // slice length
#define LW      64     // shapelet length
#define NW      565    // T - LW + 1 windows  (= 5 * 113)
#define EW      128    // output embedding
#define XSTRIDE 8192   // C * LEN_TS
#define XOFF    2048   // DIM * LEN_TS
#define WPT     5      // windows per thread (113 active threads * 5 = 565)

// ws float layout:
//   [0..127]  combined bias: b1[e] - (shapelet . W2[e] + b2[e])
//   [128]     s_ci   [129] ss2 = sum(shapelet^2)
//   [132..]   W1T[j*128 + e] = W1[e*64 + j]
#define WS_SCI 128
#define WS_SS2 129
#define WS_W1T 132
#define WS_NEEDED ((WS_W1T + EW * LW) * sizeof(float))

__global__ __launch_bounds__(64) void prep_kernel(
        const float* __restrict__ shapelet,
        const float* __restrict__ b1,
        const float* __restrict__ W1,
        const float* __restrict__ W2,
        const float* __restrict__ b2,
        float* __restrict__ ws, int use_wt) {
    const int b = blockIdx.x;
    const int j = threadIdx.x;           // 0..63
    const float sh = shapelet[j];
    if (b < EW) {
        const int e = b;
        float dot = sh * W2[e * LW + j];
        #pragma unroll
        for (int off = 32; off; off >>= 1) dot += __shfl_xor(dot, off, 64);
        if (use_wt) ws[WS_W1T + j * EW + e] = W1[e * LW + j];
        if (j == 0) ws[e] = b1[e] - (dot + b2[e]);
    } else {
        float shn = __shfl_down(sh, 1, 64);
        float d = (j < LW - 1) ? (shn - sh) * (shn - sh) : 0.f;
        float q = sh * sh;
        #pragma unroll
        for (int off = 32; off; off >>= 1) {
            d += __shfl_xor(d, off, 64);
            q += __shfl_xor(q, off, 64);
        }
        if (j == 0) { ws[WS_SCI] = sqrtf(d + 0.001f); ws[WS_SS2] = q; }
    }
}

__global__ __launch_bounds__(128, 8) void shapeblock_kernel(
        const float* __restrict__ x,
        const float* __restrict__ shapelet,
        const float* __restrict__ W1,
        const float* __restrict__ ws,
        float* __restrict__ out, int use_wt) {
    __shared__ __align__(16) float sp[T];        // 628 floats, max idx 627
    __shared__ unsigned long long red[2];

    const int b   = blockIdx.x;
    const int tid = threadIdx.x;   // 0..127, two waves

    // ---- stage row: 157 float4, coalesced across 128 lanes ----
    const float4* xr4 = (const float4*)(x + (size_t)b * XSTRIDE + XOFF);
    float4* sp4 = (float4*)sp;
    sp4[tid] = xr4[tid];
    if (tid < T / 4 - 128) sp4[tid + 128] = xr4[tid + 128];
    const float s_ci = ws[WS_SCI];
    const float ss2  = ws[WS_SS2];
    __syncthreads();

    // threads 113..127: clamp to w0=0 -> bit-identical keys to thread 0,
    // argmin result unaffected, no OOB reads.
    const int w0 = (tid * WPT < NW) ? tid * WPT : 0;

    // ---- streaming corr for 5 windows + window-0 sums via register ring ----
    float ring[WPT], acc[WPT], head[WPT];
    #pragma unroll
    for (int i = 0; i < WPT; ++i) {
        ring[i] = sp[w0 + i];
        head[i] = ring[i];
        acc[i]  = 0.f;
    }
    float sd = 0.f, sw2 = 0.f, prev = 0.f;
    #pragma unroll
    for (int j = 0; j < LW; ++j) {
        const float sj = shapelet[j];     // uniform -> scalar load
        const float v  = ring[j % WPT];   // = sp[w0 + j]
        sw2 = fmaf(v, v, sw2);
        if (j > 0) { float d = v - prev; sd = fmaf(d, d, sd); }
        prev = v;
        #pragma unroll
        for (int i = 0; i < WPT; ++i)
            acc[i] = fmaf(ring[(j + i) % WPT], sj, acc[i]);
        if (j < LW - 1) ring[j % WPT] = sp[w0 + j + WPT];
    }
    // invariant: ring[(3 + i) % 5] == sp[w0 + 63 + i], i = 0..4

    // ---- per-window CID + argmin key; O(1) slides from regs only ----
    unsigned long long key = ~0ull;
    #pragma unroll
    for (int k = 0; k < WPT; ++k) {
        const int w = w0 + k;
        float pci = sqrtf(sd + 0.001f);
        float ed  = sqrtf(fmaxf(fmaf(-2.f, acc[k], sw2 + ss2), 0.f));
        float cf  = fminf(fmaxf(pci, s_ci) / fminf(pci, s_ci), 3.0f);
        float cid = ed * cf;
        unsigned long long kk =
            ((unsigned long long)__float_as_uint(cid) << 32) | (unsigned)w;
        key = kk < key ? kk : key;
        if (k < WPT - 1) {
            float dold = head[k + 1] - head[k];
            float dnew = ring[(4 + k) % WPT] - ring[(3 + k) % WPT];
            sd  = fmaf(dnew, dnew, fmaf(-dold, dold, sd));
            float vold = head[k], vnew = ring[(4 + k) % WPT];
            sw2 = fmaf(vnew, vnew, fmaf(-vold, vold, sw2));
        }
    }

    // ---- argmin: wave butterfly, then 2-entry LDS min across waves ----
    #pragma unroll
    for (int off = 32; off; off >>= 1) {
        unsigned long long o =
            (unsigned long long)__shfl_xor((long long)key, off, 64);
        key = o < key ? o : key;
    }
    if ((tid & 63) == 0) red[tid >> 6] = key;
    __syncthreads();
    unsigned long long k0 = red[0], k1 = red[1];
    const int widx = (int)((k0 < k1 ? k0 : k1) & 0xffffffffu);

    // ---- GEMV: out[b][e] = window . W1[e] + bias[e], e = tid ----
    float a0 = ws[tid];
    if (use_wt) {
        const float* wt = ws + WS_W1T;
        #pragma unroll
        for (int j = 0; j < LW; ++j)
            a0 = fmaf(sp[widx + j], wt[j * EW + tid], a0);  // coalesced
    } else {
        #pragma unroll
        for (int j = 0; j < LW; ++j)
            a0 = fmaf(sp[widx + j], W1[tid * LW + j], a0);
    }
    out[(size_t)b * EW + tid] = a0;
}

extern "C" void kernel_launch(void* const* d_in, const int* in_sizes, int n_in,
                              void* d_out, int out_size, void* d_ws, size_t ws_size,
                              hipStream_t stream) {
    const float* x        = (const float*)d_in[0];
    const float* shapelet = (const float*)d_in[1];
    const float* W1       = (const float*)d_in[2];
    const float* b1       = (const float*)d_in[3];
    const float* W2       = (const float*)d_in[4];
    const float* b2       = (const float*)d_in[5];
    float* out = (float*)d_out;
    float* ws  = (float*)d_ws;

    const int use_wt = (ws_size >= WS_NEEDED) ? 1 : 0;

    prep_kernel<<<EW + 1, 64, 0, stream>>>(shapelet, b1, W1, W2, b2, ws, use_wt);
    shapeblock_kernel<<<NB, 128, 0, stream>>>(x, shapelet, W1, ws, out, use_wt);
}

// Round 6
// 23.822 us; speedup vs baseline: 4.2496x; 1.0887x over previous
//
#include <hip/hip_runtime.h>
#include <math.h>

#define NB      4096   // batch rows
#define T       628    // slice length
#define LW      64     // shapelet length
#define NW      565    // T - LW + 1 windows (= 5 * 113)
#define EW      128    // output embedding
#define XSTRIDE 8192   // C * LEN_TS
#define XOFF    2048   // DIM * LEN_TS
#define WPT     5      // windows per thread (113 active of 128)

// Single fused kernel: 2 rows per block, 256 threads (4 waves).
// waves 0,1 -> row0 windows; waves 2,3 -> row1 windows.
// GEMV phase: threads 0..127 compute W1 dot for BOTH rows (halves W1 traffic),
// threads 128..255 compute shapelet.W2[e] in parallel; combine via LDS.
__global__ __launch_bounds__(256, 8) void shapeblock_fused(
        const float* __restrict__ x,
        const float* __restrict__ shapelet,
        const float* __restrict__ W1,
        const float* __restrict__ b1,
        const float* __restrict__ W2,
        const float* __restrict__ b2,
        float* __restrict__ out) {
    __shared__ __align__(16) float sp[2][T];
    __shared__ unsigned long long red[4];
    __shared__ float s2dot[EW];

    const int tid  = threadIdx.x;    // 0..255
    const int half = tid >> 7;       // which row of the pair
    const int l    = tid & 127;      // lane within half
    const int lane = tid & 63;       // lane within wave
    const int row0 = blockIdx.x * 2;

    // ---- stage the two rows (each half stages its own, float4 coalesced) ----
    const float4* xr4 = (const float4*)(x + (size_t)(row0 + half) * XSTRIDE + XOFF);
    float4* sp4 = (float4*)sp[half];
    sp4[l] = xr4[l];
    if (l < T / 4 - 128) sp4[l + 128] = xr4[l + 128];

    // ---- shapelet stats, per-wave redundant (no extra syncs) ----
    const float shv = shapelet[lane];
    float shn = __shfl_down(shv, 1, 64);
    float dsum = (lane < LW - 1) ? (shn - shv) * (shn - shv) : 0.f;
    float qsum = shv * shv;
    #pragma unroll
    for (int off = 32; off; off >>= 1) {
        dsum += __shfl_xor(dsum, off, 64);
        qsum += __shfl_xor(qsum, off, 64);
    }
    const float s_ci = sqrtf(dsum + 0.001f);
    const float ss2  = qsum;
    __syncthreads();

    const float* mysp = sp[half];
    // lanes 113..127 clamp to w0=0 -> duplicate thread-0 keys, argmin unaffected
    const int w0 = (l * WPT < NW) ? l * WPT : 0;

    // ---- streaming corr for 5 windows + window-0 sums via register ring ----
    float ring[WPT], acc[WPT], head[WPT];
    #pragma unroll
    for (int i = 0; i < WPT; ++i) {
        ring[i] = mysp[w0 + i];
        head[i] = ring[i];
        acc[i]  = 0.f;
    }
    float sd = 0.f, sw2 = 0.f, prev = 0.f;
    #pragma unroll
    for (int j = 0; j < LW; ++j) {
        const float sj = shapelet[j];   // uniform -> scalar load
        const float v  = ring[j % WPT]; // = mysp[w0 + j]
        sw2 = fmaf(v, v, sw2);
        if (j > 0) { float d = v - prev; sd = fmaf(d, d, sd); }
        prev = v;
        #pragma unroll
        for (int i = 0; i < WPT; ++i)
            acc[i] = fmaf(ring[(j + i) % WPT], sj, acc[i]);
        if (j < LW - 1) ring[j % WPT] = mysp[w0 + j + WPT];
    }
    // invariant: ring[(3 + i) % 5] == mysp[w0 + 63 + i], i = 0..4

    // ---- per-window CID + argmin key; O(1) slides from registers ----
    unsigned long long key = ~0ull;
    #pragma unroll
    for (int k = 0; k < WPT; ++k) {
        const int w = w0 + k;
        float pci = sqrtf(sd + 0.001f);
        float ed  = sqrtf(fmaxf(fmaf(-2.f, acc[k], sw2 + ss2), 0.f));
        float cf  = fminf(fmaxf(pci, s_ci) / fminf(pci, s_ci), 3.0f);
        float cid = ed * cf;
        unsigned long long kk =
            ((unsigned long long)__float_as_uint(cid) << 32) | (unsigned)w;
        key = kk < key ? kk : key;
        if (k < WPT - 1) {
            float dold = head[k + 1] - head[k];
            float dnew = ring[(4 + k) % WPT] - ring[(3 + k) % WPT];
            sd  = fmaf(dnew, dnew, fmaf(-dold, dold, sd));
            float vold = head[k], vnew = ring[(4 + k) % WPT];
            sw2 = fmaf(vnew, vnew, fmaf(-vold, vold, sw2));
        }
    }

    // ---- argmin: per-wave butterfly, then combine 2 waves per row ----
    #pragma unroll
    for (int off = 32; off; off >>= 1) {
        unsigned long long o =
            (unsigned long long)__shfl_xor((long long)key, off, 64);
        key = o < key ? o : key;
    }
    if (lane == 0) red[tid >> 6] = key;
    __syncthreads();
    unsigned long long r0 = red[0], r1 = red[1], r2 = red[2], r3 = red[3];
    const int widx0 = (int)((r0 < r1 ? r0 : r1) & 0xffffffffu);
    const int widx1 = (int)((r2 < r3 ? r2 : r3) & 0xffffffffu);

    // ---- split phase: lower half W1-GEMV (both rows), upper half W2 dot ----
    float a0 = 0.f, a1 = 0.f;
    if (half == 0) {
        const float4* w1r = (const float4*)(W1 + l * LW);
        #pragma unroll
        for (int k = 0; k < LW / 4; ++k) {
            float4 wv = w1r[k];
            const int j = 4 * k;
            a0 = fmaf(sp[0][widx0 + j    ], wv.x, a0);
            a0 = fmaf(sp[0][widx0 + j + 1], wv.y, a0);
            a0 = fmaf(sp[0][widx0 + j + 2], wv.z, a0);
            a0 = fmaf(sp[0][widx0 + j + 3], wv.w, a0);
            a1 = fmaf(sp[1][widx1 + j    ], wv.x, a1);
            a1 = fmaf(sp[1][widx1 + j + 1], wv.y, a1);
            a1 = fmaf(sp[1][widx1 + j + 2], wv.z, a1);
            a1 = fmaf(sp[1][widx1 + j + 3], wv.w, a1);
        }
    } else {
        const float4* w2r = (const float4*)(W2 + l * LW);
        float d = 0.f;
        #pragma unroll
        for (int k = 0; k < LW / 4; ++k) {
            float4 wv = w2r[k];
            const int j = 4 * k;
            d = fmaf(shapelet[j    ], wv.x, d);   // uniform scalar loads
            d = fmaf(shapelet[j + 1], wv.y, d);
            d = fmaf(shapelet[j + 2], wv.z, d);
            d = fmaf(shapelet[j + 3], wv.w, d);
        }
        s2dot[l] = d;
    }
    __syncthreads();

    if (half == 0) {
        const float bias = b1[l] - b2[l] - s2dot[l];
        out[(size_t)row0 * EW + l]       = a0 + bias;
        out[(size_t)(row0 + 1) * EW + l] = a1 + bias;
    }
}

extern "C" void kernel_launch(void* const* d_in, const int* in_sizes, int n_in,
                              void* d_out, int out_size, void* d_ws, size_t ws_size,
                              hipStream_t stream) {
    const float* x        = (const float*)d_in[0];
    const float* shapelet = (const float*)d_in[1];
    const float* W1       = (const float*)d_in[2];
    const float* b1       = (const float*)d_in[3];
    const float* W2       = (const float*)d_in[4];
    const float* b2       = (const float*)d_in[5];
    float* out = (float*)d_out;

    shapeblock_fused<<<NB / 2, 256, 0, stream>>>(x, shapelet, W1, b1, W2, b2, out);
}